// Round 2
// baseline (668.247 us; speedup 1.0000x reference)
//
#include <hip/hip_runtime.h>
#include <math.h>

#define BB 64
#define RR 6912
#define II 8
#define CC 10
#define OO 16
#define NCH 216         // route chunks
#define RC 32           // routes per chunk (NCH*RC == RR)
#define TR 4            // routes per tile (== waves per block)
#define NT 8            // tiles per chunk (TR*NT == RC)
#define LDSF 4608       // max(2*512 W dbuf, 256*18 epilogue)

// ---------------- transpose kernel: x[B][R][8] -> xt[R][B][8] ----------------
__global__ __launch_bounds__(256) void transpose_kernel(
    const float* __restrict__ x, float4* __restrict__ xt4)
{
    __shared__ float4 lds4[64 * 34];   // [rl][bl*2+h], rl-stride 34 to break banks
    const int rblk = blockIdx.x >> 2;
    const int bblk = blockIdx.x & 3;
    const int r0 = rblk * 64, b0 = bblk * 16;
    const int t = threadIdx.x;

    {   // read: lanes sweep r (x rows are r-major contiguous)
        const int rl = t & 63;
        const int bl0 = t >> 6;        // 0..3
#pragma unroll
        for (int kb = 0; kb < 4; ++kb) {
            const int bl = kb * 4 + bl0;   // 0..15
            const float4* src = (const float4*)(x + ((size_t)(b0 + bl) * RR + (r0 + rl)) * II);
            lds4[rl * 34 + bl * 2 + 0] = src[0];
            lds4[rl * 34 + bl * 2 + 1] = src[1];
        }
    }
    __syncthreads();
    {   // write: lanes sweep b (xt rows are b-major contiguous)
        const int bl = t & 15;
        const int rw0 = t >> 4;        // 0..15
#pragma unroll
        for (int kr = 0; kr < 4; ++kr) {
            const int rw = kr * 16 + rw0;  // 0..63
            float4 a = lds4[rw * 34 + bl * 2 + 0];
            float4 bq = lds4[rw * 34 + bl * 2 + 1];
            float4* dst = xt4 + ((size_t)(r0 + rw) * BB + (b0 + bl)) * 2;
            dst[0] = a; dst[1] = bq;
        }
    }
}

// ---------------- pass kernel ----------------
// MODE 0: uniform probs -> plain sum of priors
// MODE 1: logits = dot(priors, out0)        (online softmax)
// MODE 2: logits = dot(priors, out0+out1)   (online softmax)
template <int MODE>
__global__ __launch_bounds__(256) void pass_kernel(
    const float4* __restrict__ xt4, const float4* __restrict__ w4,
    const float* __restrict__ outv_in,
    float* __restrict__ pacc, float* __restrict__ pm, float* __restrict__ pz)
{
    __shared__ __align__(16) float lds_raw[LDSF];
    float4* wbuf = (float4*)lds_raw;   // 2 buffers x 128 float4 (4 routes' W)

    const int bid = blockIdx.x;
    const int c = bid / NCH;
    const int chunk = bid - c * NCH;
    const int t = threadIdx.x;
    const int b = t & 63;
    const int j = t >> 6;              // wave id == route slot in tile
    const int r0base = chunk * RC;

    float acc[OO];
#pragma unroll
    for (int o = 0; o < OO; ++o) acc[o] = 0.f;
    float m = -INFINITY, Z = 0.f;

    float ov[OO];
    if (MODE != 0) {
        const float4* op = (const float4*)(outv_in + ((size_t)c * BB + b) * OO);
#pragma unroll
        for (int q = 0; q < 4; ++q) {
            float4 v = op[q];
            ov[q * 4 + 0] = v.x; ov[q * 4 + 1] = v.y; ov[q * 4 + 2] = v.z; ov[q * 4 + 3] = v.w;
        }
    }

    const size_t wbase = (size_t)c * RR * 32;   // float4 index of W[c][0][0][0]

    // preload tile 0
    float4 wreg;
    if (t < 128) wreg = w4[wbase + (size_t)r0base * 32 + t];
    {
    }
    int r = r0base + j;
    float4 xc0 = xt4[((size_t)r * BB + b) * 2];
    float4 xc1 = xt4[((size_t)r * BB + b) * 2 + 1];

    int pbuf = 0;
    for (int tile = 0; tile < NT; ++tile) {
        if (t < 128) wbuf[pbuf * 128 + t] = wreg;
        __syncthreads();

        // prefetch next tile (wraps to 0 on last iter; harmless)
        const int ntile = (tile + 1 < NT) ? tile + 1 : 0;
        if (t < 128) wreg = w4[wbase + (size_t)(r0base + ntile * TR) * 32 + t];
        const int rn = r0base + ntile * TR + j;
        float4 xn0 = xt4[((size_t)rn * BB + b) * 2];
        float4 xn1 = xt4[((size_t)rn * BB + b) * 2 + 1];

        // compute priors for this tile's route slot j, batch b, all 16 o
        const float4* wv = wbuf + pbuf * 128 + j * 32;  // [i][oq] float4s
        float xr[II] = {xc0.x, xc0.y, xc0.z, xc0.w, xc1.x, xc1.y, xc1.z, xc1.w};
        float p[OO];
#pragma unroll
        for (int o = 0; o < OO; ++o) p[o] = 0.f;
#pragma unroll
        for (int i = 0; i < II; ++i) {
            float4 w0 = wv[i * 4 + 0];
            float4 w1 = wv[i * 4 + 1];
            float4 w2 = wv[i * 4 + 2];
            float4 w3 = wv[i * 4 + 3];
            p[0] = fmaf(xr[i], w0.x, p[0]);  p[1] = fmaf(xr[i], w0.y, p[1]);
            p[2] = fmaf(xr[i], w0.z, p[2]);  p[3] = fmaf(xr[i], w0.w, p[3]);
            p[4] = fmaf(xr[i], w1.x, p[4]);  p[5] = fmaf(xr[i], w1.y, p[5]);
            p[6] = fmaf(xr[i], w1.z, p[6]);  p[7] = fmaf(xr[i], w1.w, p[7]);
            p[8] = fmaf(xr[i], w2.x, p[8]);  p[9] = fmaf(xr[i], w2.y, p[9]);
            p[10] = fmaf(xr[i], w2.z, p[10]); p[11] = fmaf(xr[i], w2.w, p[11]);
            p[12] = fmaf(xr[i], w3.x, p[12]); p[13] = fmaf(xr[i], w3.y, p[13]);
            p[14] = fmaf(xr[i], w3.z, p[14]); p[15] = fmaf(xr[i], w3.w, p[15]);
        }

        if (MODE == 0) {
#pragma unroll
            for (int o = 0; o < OO; ++o) acc[o] += p[o];
        } else {
            float d = 0.f;
#pragma unroll
            for (int o = 0; o < OO; ++o) d = fmaf(p[o], ov[o], d);
            const float nm  = fmaxf(m, d);
            const float sc  = __expf(m - nm);   // 0 on first route (m=-inf, nm finite)
            const float wgt = __expf(d - nm);
            Z = Z * sc + wgt;
#pragma unroll
            for (int o = 0; o < OO; ++o) acc[o] = fmaf(acc[o], sc, wgt * p[o]);
            m = nm;
        }

        xc0 = xn0; xc1 = xn1;
        pbuf ^= 1;
    }

    // merge the TR per-wave partials -> one partial per (c,chunk,b)
    __syncthreads();
    {
        float* myred = lds_raw + t * 18;
#pragma unroll
        for (int o = 0; o < OO; ++o) myred[o] = acc[o];
        myred[16] = m;
        myred[17] = Z;
    }
    __syncthreads();
    if (t < BB) {
        const int b0 = t;
        float A2[OO];
#pragma unroll
        for (int o = 0; o < OO; ++o) A2[o] = 0.f;
        float M2 = -INFINITY, Z2 = 0.f;
        if (MODE == 0) {
            for (int k = 0; k < TR; ++k) {
                const float* rp = lds_raw + (k * BB + b0) * 18;
#pragma unroll
                for (int o = 0; o < OO; ++o) A2[o] += rp[o];
            }
        } else {
            for (int k = 0; k < TR; ++k)
                M2 = fmaxf(M2, lds_raw[(k * BB + b0) * 18 + 16]);
            for (int k = 0; k < TR; ++k) {
                const float* rp = lds_raw + (k * BB + b0) * 18;
                const float e = __expf(rp[16] - M2);
                Z2 += rp[17] * e;
#pragma unroll
                for (int o = 0; o < OO; ++o) A2[o] = fmaf(rp[o], e, A2[o]);
            }
        }
        const int pidx = (c * NCH + chunk) * BB + b0;
        float* ap = pacc + (size_t)pidx * OO;
#pragma unroll
        for (int o = 0; o < OO; o += 4)
            *(float4*)(ap + o) = make_float4(A2[o], A2[o + 1], A2[o + 2], A2[o + 3]);
        if (MODE != 0) { pm[pidx] = M2; pz[pidx] = Z2; }
    }
}

// ---------------- combine kernel ----------------
// One block per (c,b). 256 threads = 16 o x 16 partial-groups.
// MODE 0: s = sum/R, out0 = squash(s)
// MODE 1: outsum = out0 + squash(merged)
// MODE 2: final  = squash(merged)
template <int MODE>
__global__ __launch_bounds__(256) void combine_kernel(
    const float* __restrict__ pacc, const float* __restrict__ pm,
    const float* __restrict__ pz, const float* __restrict__ out0,
    float* __restrict__ outw)
{
    __shared__ float lsum[256];
    __shared__ float lz[16], lm[16];
    const int cb = blockIdx.x;          // c*64 + b
    const int c = cb >> 6, b = cb & 63;
    const int t = threadIdx.x;
    const int o = t & 15, g = t >> 4;

    float s = 0.f;
    if (MODE == 0) {
        for (int p = g; p < NCH; p += 16)
            s += pacc[((size_t)(c * NCH + p) * BB + b) * OO + o];
        lsum[t] = s;
        __syncthreads();
        if (g == 0) {
            for (int k = 1; k < 16; ++k) s += lsum[k * 16 + o];
            s *= (1.0f / RR);
        }
    } else {
        float M = -INFINITY;
        for (int p = g; p < NCH; p += 16)
            M = fmaxf(M, pm[(c * NCH + p) * BB + b]);
        if (o == 0) lm[g] = M;
        __syncthreads();
        float Mg = lm[0];
#pragma unroll
        for (int k = 1; k < 16; ++k) Mg = fmaxf(Mg, lm[k]);
        float Zl = 0.f;
        for (int p = g; p < NCH; p += 16) {
            const int pi = (c * NCH + p) * BB + b;
            const float e = __expf(pm[pi] - Mg);
            s = fmaf(pacc[(size_t)pi * OO + o], e, s);
            Zl = fmaf(pz[pi], e, Zl);
        }
        lsum[t] = s;
        if (o == 0) lz[g] = Zl;
        __syncthreads();
        if (g == 0) {
            for (int k = 1; k < 16; ++k) s += lsum[k * 16 + o];
            float Zt = 0.f;
#pragma unroll
            for (int k = 0; k < 16; ++k) Zt += lz[k];
            s /= Zt;
        }
    }

    if (g == 0) {   // lanes 0..15 of wave 0 hold s[o]
        float sq = s * s;
#pragma unroll
        for (int w = 1; w < 16; w <<= 1) sq += __shfl_xor(sq, w);
        float val = s * sqrtf(sq) / (1.f + sq);
        if (MODE == 1) val += out0[(size_t)cb * OO + o];
        outw[(size_t)cb * OO + o] = val;
    }
}

extern "C" void kernel_launch(void* const* d_in, const int* in_sizes, int n_in,
                              void* d_out, int out_size, void* d_ws, size_t ws_size,
                              hipStream_t stream)
{
    const float* x = (const float*)d_in[0];
    const float* w = (const float*)d_in[1];
    float* out = (float*)d_out;

    float* ws = (float*)d_ws;
    float* xt     = ws;                                   // RR*BB*II     = 3,538,944
    float* pacc   = xt + (size_t)RR * BB * II;            // CC*NCH*BB*OO = 2,211,840
    float* pm     = pacc + (size_t)CC * NCH * BB * OO;    // CC*NCH*BB
    float* pz     = pm + CC * NCH * BB;
    float* out0   = pz + CC * NCH * BB;                   // CC*BB*OO
    float* outsum = out0 + CC * BB * OO;                  // CC*BB*OO

    float4* xt4 = (float4*)xt;
    const float4* w4 = (const float4*)w;

    transpose_kernel<<<dim3((RR / 64) * 4), dim3(256), 0, stream>>>(x, xt4);

    const dim3 gp(CC * NCH), bp(256);
    const dim3 gc(CC * BB), bc(256);

    pass_kernel<0><<<gp, bp, 0, stream>>>(xt4, w4, nullptr, pacc, pm, pz);
    combine_kernel<0><<<gc, bc, 0, stream>>>(pacc, pm, pz, nullptr, out0);
    pass_kernel<1><<<gp, bp, 0, stream>>>(xt4, w4, out0, pacc, pm, pz);
    combine_kernel<1><<<gc, bc, 0, stream>>>(pacc, pm, pz, out0, outsum);
    pass_kernel<2><<<gp, bp, 0, stream>>>(xt4, w4, outsum, pacc, pm, pz);
    combine_kernel<2><<<gc, bc, 0, stream>>>(pacc, pm, pz, nullptr, out);
}

// Round 3
// 204.223 us; speedup vs baseline: 3.2721x; 3.2721x over previous
//
#include <hip/hip_runtime.h>
#include <math.h>

#define BB 64
#define RR 6912
#define II 8
#define CC 10
#define OO 16
#define NCH 216         // route chunks
#define RC 32           // routes per chunk (NCH*RC == RR)
#define TR 4            // routes per tile (== waves per block)
#define NT 8            // tiles per chunk (TR*NT == RC)
#define LDSF 4608       // max(512 W tile, 256*18 epilogue) floats

// ---------------- transpose kernel: x[B][R][8] -> xt[R][B][8] ----------------
__global__ __launch_bounds__(256) void transpose_kernel(
    const float* __restrict__ x, float4* __restrict__ xt4)
{
    __shared__ float4 lds4[64 * 34];   // [rl][bl*2+h], rl-stride 34 to break banks
    const int rblk = blockIdx.x >> 2;
    const int bblk = blockIdx.x & 3;
    const int r0 = rblk * 64, b0 = bblk * 16;
    const int t = threadIdx.x;

    {   // read: lanes sweep r (x rows are r-major contiguous)
        const int rl = t & 63;
        const int bl0 = t >> 6;        // 0..3
#pragma unroll
        for (int kb = 0; kb < 4; ++kb) {
            const int bl = kb * 4 + bl0;   // 0..15
            const float4* src = (const float4*)(x + ((size_t)(b0 + bl) * RR + (r0 + rl)) * II);
            lds4[rl * 34 + bl * 2 + 0] = src[0];
            lds4[rl * 34 + bl * 2 + 1] = src[1];
        }
    }
    __syncthreads();
    {   // write: lanes sweep b (xt rows are b-major contiguous)
        const int bl = t & 15;
        const int rw0 = t >> 4;        // 0..15
#pragma unroll
        for (int kr = 0; kr < 4; ++kr) {
            const int rw = kr * 16 + rw0;  // 0..63
            float4 a = lds4[rw * 34 + bl * 2 + 0];
            float4 bq = lds4[rw * 34 + bl * 2 + 1];
            float4* dst = xt4 + ((size_t)(r0 + rw) * BB + (b0 + bl)) * 2;
            dst[0] = a; dst[1] = bq;
        }
    }
}

// ---------------- pass kernel ----------------
// MODE 0: uniform probs -> plain sum of priors
// MODE 1: logits = dot(priors, out0)        (online softmax)
// MODE 2: logits = dot(priors, out0+out1)   (online softmax)
template <int MODE>
__global__ __launch_bounds__(256, 4) void pass_kernel(
    const float4* __restrict__ xt4, const float4* __restrict__ w4,
    const float* __restrict__ outv_in,
    float* __restrict__ pacc, float* __restrict__ pm, float* __restrict__ pz)
{
    __shared__ __align__(16) float lds_raw[LDSF];
    float4* wbuf = (float4*)lds_raw;   // 128 float4 = one tile (4 routes) of W

    const int bid = blockIdx.x;
    const int c = bid / NCH;
    const int chunk = bid - c * NCH;
    const int t = threadIdx.x;
    const int b = t & 63;
    const int j = t >> 6;              // wave id == route slot in tile
    const int r0base = chunk * RC;

    float acc[OO];
#pragma unroll
    for (int o = 0; o < OO; ++o) acc[o] = 0.f;
    float m = -INFINITY, Z = 0.f;

    float ov[OO];
    if (MODE != 0) {
        const float4* op = (const float4*)(outv_in + ((size_t)c * BB + b) * OO);
#pragma unroll
        for (int q = 0; q < 4; ++q) {
            float4 v = op[q];
            ov[q * 4 + 0] = v.x; ov[q * 4 + 1] = v.y; ov[q * 4 + 2] = v.z; ov[q * 4 + 3] = v.w;
        }
    }

    const size_t wbase = (size_t)c * RR * 32;   // float4 index of W[c][0][0][0]

#pragma unroll 1
    for (int tile = 0; tile < NT; ++tile) {
        const int r0 = r0base + tile * TR;
        __syncthreads();
        if (t < 128) wbuf[t] = w4[wbase + (size_t)r0 * 32 + t];
        __syncthreads();

        // x for this thread's (route, batch) — coalesced direct global read
        const int r = r0 + j;
        const float4 xc0 = xt4[((size_t)r * BB + b) * 2];
        const float4 xc1 = xt4[((size_t)r * BB + b) * 2 + 1];
        const float xr[II] = {xc0.x, xc0.y, xc0.z, xc0.w, xc1.x, xc1.y, xc1.z, xc1.w};

        const float4* wv = wbuf + j * 32;  // [i][oq] float4s, wave-uniform broadcast
        float p[OO];
#pragma unroll
        for (int o = 0; o < OO; ++o) p[o] = 0.f;
#pragma unroll
        for (int i = 0; i < II; ++i) {
            float4 w0 = wv[i * 4 + 0];
            float4 w1 = wv[i * 4 + 1];
            float4 w2 = wv[i * 4 + 2];
            float4 w3 = wv[i * 4 + 3];
            p[0]  = fmaf(xr[i], w0.x, p[0]);   p[1]  = fmaf(xr[i], w0.y, p[1]);
            p[2]  = fmaf(xr[i], w0.z, p[2]);   p[3]  = fmaf(xr[i], w0.w, p[3]);
            p[4]  = fmaf(xr[i], w1.x, p[4]);   p[5]  = fmaf(xr[i], w1.y, p[5]);
            p[6]  = fmaf(xr[i], w1.z, p[6]);   p[7]  = fmaf(xr[i], w1.w, p[7]);
            p[8]  = fmaf(xr[i], w2.x, p[8]);   p[9]  = fmaf(xr[i], w2.y, p[9]);
            p[10] = fmaf(xr[i], w2.z, p[10]);  p[11] = fmaf(xr[i], w2.w, p[11]);
            p[12] = fmaf(xr[i], w3.x, p[12]);  p[13] = fmaf(xr[i], w3.y, p[13]);
            p[14] = fmaf(xr[i], w3.z, p[14]);  p[15] = fmaf(xr[i], w3.w, p[15]);
        }

        if (MODE == 0) {
#pragma unroll
            for (int o = 0; o < OO; ++o) acc[o] += p[o];
        } else {
            float d = 0.f;
#pragma unroll
            for (int o = 0; o < OO; ++o) d = fmaf(p[o], ov[o], d);
            const float nm  = fmaxf(m, d);
            const float sc  = __expf(m - nm);   // 0 on first route (m=-inf, nm finite)
            const float wgt = __expf(d - nm);
            Z = Z * sc + wgt;
#pragma unroll
            for (int o = 0; o < OO; ++o) acc[o] = fmaf(acc[o], sc, wgt * p[o]);
            m = nm;
        }
    }

    // merge the TR per-wave partials -> one partial per (c,chunk,b)
    __syncthreads();
    {
        float* myred = lds_raw + t * 18;
#pragma unroll
        for (int o = 0; o < OO; ++o) myred[o] = acc[o];
        myred[16] = m;
        myred[17] = Z;
    }
    __syncthreads();
    if (t < BB) {
        const int b0 = t;
        float A2[OO];
#pragma unroll
        for (int o = 0; o < OO; ++o) A2[o] = 0.f;
        float M2 = -INFINITY, Z2 = 0.f;
        if (MODE == 0) {
            for (int k = 0; k < TR; ++k) {
                const float* rp = lds_raw + (k * BB + b0) * 18;
#pragma unroll
                for (int o = 0; o < OO; ++o) A2[o] += rp[o];
            }
        } else {
            for (int k = 0; k < TR; ++k)
                M2 = fmaxf(M2, lds_raw[(k * BB + b0) * 18 + 16]);
            for (int k = 0; k < TR; ++k) {
                const float* rp = lds_raw + (k * BB + b0) * 18;
                const float e = __expf(rp[16] - M2);
                Z2 += rp[17] * e;
#pragma unroll
                for (int o = 0; o < OO; ++o) A2[o] = fmaf(rp[o], e, A2[o]);
            }
        }
        const int pidx = (c * NCH + chunk) * BB + b0;
        float* ap = pacc + (size_t)pidx * OO;
#pragma unroll
        for (int o = 0; o < OO; o += 4)
            *(float4*)(ap + o) = make_float4(A2[o], A2[o + 1], A2[o + 2], A2[o + 3]);
        if (MODE != 0) { pm[pidx] = M2; pz[pidx] = Z2; }
    }
}

// ---------------- combine kernel ----------------
// One block per (c,b). 256 threads = 16 o x 16 partial-groups.
// MODE 0: s = sum/R, out0 = squash(s)
// MODE 1: outsum = out0 + squash(merged)
// MODE 2: final  = squash(merged)
template <int MODE>
__global__ __launch_bounds__(256) void combine_kernel(
    const float* __restrict__ pacc, const float* __restrict__ pm,
    const float* __restrict__ pz, const float* __restrict__ out0,
    float* __restrict__ outw)
{
    __shared__ float lsum[256];
    __shared__ float lz[16], lm[16];
    const int cb = blockIdx.x;          // c*64 + b
    const int c = cb >> 6, b = cb & 63;
    const int t = threadIdx.x;
    const int o = t & 15, g = t >> 4;

    float s = 0.f;
    if (MODE == 0) {
        for (int p = g; p < NCH; p += 16)
            s += pacc[((size_t)(c * NCH + p) * BB + b) * OO + o];
        lsum[t] = s;
        __syncthreads();
        if (g == 0) {
            for (int k = 1; k < 16; ++k) s += lsum[k * 16 + o];
            s *= (1.0f / RR);
        }
    } else {
        float M = -INFINITY;
        for (int p = g; p < NCH; p += 16)
            M = fmaxf(M, pm[(c * NCH + p) * BB + b]);
        if (o == 0) lm[g] = M;
        __syncthreads();
        float Mg = lm[0];
#pragma unroll
        for (int k = 1; k < 16; ++k) Mg = fmaxf(Mg, lm[k]);
        float Zl = 0.f;
        for (int p = g; p < NCH; p += 16) {
            const int pi = (c * NCH + p) * BB + b;
            const float e = __expf(pm[pi] - Mg);
            s = fmaf(pacc[(size_t)pi * OO + o], e, s);
            Zl = fmaf(pz[pi], e, Zl);
        }
        lsum[t] = s;
        if (o == 0) lz[g] = Zl;
        __syncthreads();
        if (g == 0) {
            for (int k = 1; k < 16; ++k) s += lsum[k * 16 + o];
            float Zt = 0.f;
#pragma unroll
            for (int k = 0; k < 16; ++k) Zt += lz[k];
            s /= Zt;
        }
    }

    if (g == 0) {   // lanes 0..15 of wave 0 hold s[o]
        float sq = s * s;
#pragma unroll
        for (int w = 1; w < 16; w <<= 1) sq += __shfl_xor(sq, w);
        float val = s * sqrtf(sq) / (1.f + sq);
        if (MODE == 1) val += out0[(size_t)cb * OO + o];
        outw[(size_t)cb * OO + o] = val;
    }
}

extern "C" void kernel_launch(void* const* d_in, const int* in_sizes, int n_in,
                              void* d_out, int out_size, void* d_ws, size_t ws_size,
                              hipStream_t stream)
{
    const float* x = (const float*)d_in[0];
    const float* w = (const float*)d_in[1];
    float* out = (float*)d_out;

    float* ws = (float*)d_ws;
    float* xt     = ws;                                   // RR*BB*II     = 3,538,944
    float* pacc   = xt + (size_t)RR * BB * II;            // CC*NCH*BB*OO = 2,211,840
    float* pm     = pacc + (size_t)CC * NCH * BB * OO;    // CC*NCH*BB
    float* pz     = pm + CC * NCH * BB;
    float* out0   = pz + CC * NCH * BB;                   // CC*BB*OO
    float* outsum = out0 + CC * BB * OO;                  // CC*BB*OO

    float4* xt4 = (float4*)xt;
    const float4* w4 = (const float4*)w;

    transpose_kernel<<<dim3((RR / 64) * 4), dim3(256), 0, stream>>>(x, xt4);

    const dim3 gp(CC * NCH), bp(256);
    const dim3 gc(CC * BB), bc(256);

    pass_kernel<0><<<gp, bp, 0, stream>>>(xt4, w4, nullptr, pacc, pm, pz);
    combine_kernel<0><<<gc, bc, 0, stream>>>(pacc, pm, pz, nullptr, out0);
    pass_kernel<1><<<gp, bp, 0, stream>>>(xt4, w4, out0, pacc, pm, pz);
    combine_kernel<1><<<gc, bc, 0, stream>>>(pacc, pm, pz, out0, outsum);
    pass_kernel<2><<<gp, bp, 0, stream>>>(xt4, w4, outsum, pacc, pm, pz);
    combine_kernel<2><<<gc, bc, 0, stream>>>(pacc, pm, pz, nullptr, out);
}